// Round 4
// baseline (15471.413 us; speedup 1.0000x reference)
//
#include <hip/hip_runtime.h>

typedef _Float16 f16;
typedef _Float16 f16x8 __attribute__((ext_vector_type(8)));
typedef float    f32x4 __attribute__((ext_vector_type(4)));
typedef unsigned int       u32;
typedef unsigned long long u64;

#define HD    64
#define GW    16      // real batches per group (full N-tile, no padding)
#define NT    512     // 8 waves
#define DRING 8       // ring slots per group (4 KB each)
#define CHUNK 4       // steps per flag update
#define XCH   256     // x staging chunk (timesteps)
#define SCL   2048.0f
#define ISC   (1.0f / 2048.0f)

__device__ __forceinline__ float fast_sig(float x) {
    return __builtin_amdgcn_rcpf(1.0f + __expf(-x));
}
__device__ __forceinline__ float fast_tanh(float x) {
    float e = __expf(2.0f * x);
    return (e - 1.0f) * __builtin_amdgcn_rcpf(e + 1.0f);
}
__device__ __forceinline__ f32x4 MFMA(f16x8 a, f16x8 b, f32x4 c) {
    return __builtin_amdgcn_mfma_f32_16x16x32_f16(a, b, c, 0, 0, 0);
}
// unit->k permutation (conflict-free packed publishes); kinv maps k -> unit
__device__ __forceinline__ int kinv(int k) {
    int kf = k >> 5, qk = (k >> 3) & 3, j = k & 7;
    int tile = (kf << 3) | (qk << 1) | (j & 1);
    return tile * 4 + (j >> 1);
}
__device__ __forceinline__ u32 packf16(f16 a, f16 b) {
    union { f16 h[2]; u32 u; } x; x.h[0] = a; x.h[1] = b; return x.u;
}
__device__ __forceinline__ void waitflag(u64* p, u64 need) {
    int guard = 0;
    while (__hip_atomic_load(p, __ATOMIC_ACQUIRE, __HIP_MEMORY_SCOPE_AGENT) < need) {
        __builtin_amdgcn_s_sleep(16);
        if (++guard > (1 << 26)) break;   // safety: fail visibly, don't hang
    }
}

extern "C" __global__ void init_ws_k(u64* flags) {
    int i = blockIdx.x * 256 + threadIdx.x;
    if (i < 8192) flags[i] = 0;
}

extern "C" __global__ void __launch_bounds__(NT, 2)
lstm2_pair(const float* __restrict__ x,
           const float* __restrict__ Wih0, const float* __restrict__ Whh0,
           const float* __restrict__ bih0, const float* __restrict__ bhh0,
           const float* __restrict__ Wih1, const float* __restrict__ Whh1,
           const float* __restrict__ bih1, const float* __restrict__ bhh1,
           const float* __restrict__ Wc1,  const float* __restrict__ bc1,
           const float* __restrict__ Wc2,  const float* __restrict__ bc2,
           float* __restrict__ out, char* __restrict__ ws, int T)
{
    // per-role h state, double buffered: [par][prec][kf][row=qk*16+n][j]
    __shared__ __align__(16) f16 bBuf[2][2][2][64][8];   // 8 KB
    __shared__ float xs[XCH][GW];                        // 16 KB (producer)
    __shared__ float hf[GW][HD];                         // final h1 (consumer)
    __shared__ float hid[GW][HD / 2];

    const int tid  = threadIdx.x;
    const int wave = tid >> 6;
    const int lane = tid & 63;
    const int q    = lane >> 4;
    const int n    = lane & 15;
    const int group = blockIdx.x >> 1;
    const int role  = blockIdx.x & 1;          // 0 = layer0 producer, 1 = layer1 consumer
    const int b0    = group * GW;

    u64* flags = (u64*)ws;
    u64* prodF = flags + (size_t)group * 8;
    u64* consF = flags + 4096 + (size_t)group * 8;
    char* ringG = ws + 65536 + (size_t)group * (DRING * 4096);

    { int* p = (int*)&bBuf[0][0][0][0][0];
      for (int i = tid; i < 2048; i += NT) p[i] = 0; }

    const int gA  = n & 3;              // gate of A-tile row (gate-interleaved)
    const int tt0 = 2 * wave;           // this wave's 2 tiles: tt0, tt0+1
    const int kfL = wave >> 2;          // publish kf
    const int qk  = wave & 3;
    const int row = qk * 16 + n;        // publish row
    const f32x4 z4 = {0.f, 0.f, 0.f, 0.f};

    if (role == 0) {
        // ================= producer: layer 0, K=64 =================
        f16x8 Ahi[4], Alo[4];
        f32x4 bias[2], wxv[2];
#pragma unroll
        for (int u = 0; u < 2; ++u) {
            const int tt = tt0 + u;
            const int rowA = gA * HD + tt * 4 + (n >> 2);
#pragma unroll
            for (int kf = 0; kf < 2; ++kf) {
                f16x8 hi, lo;
#pragma unroll
                for (int j = 0; j < 8; ++j) {
                    float v = Whh0[(size_t)rowA * HD + kinv(kf * 32 + q * 8 + j)];
                    f16 h = (f16)v;
                    hi[j] = h; lo[j] = (f16)((v - (float)h) * SCL);
                }
                Ahi[u * 2 + kf] = hi; Alo[u * 2 + kf] = lo;
            }
            const int uc = tt * 4 + q;
#pragma unroll
            for (int g = 0; g < 4; ++g) {
                bias[u][g] = bih0[g * HD + uc] + bhh0[g * HD + uc];
                wxv[u][g]  = Wih0[g * HD + uc];
            }
        }
        float c[2] = {0.f, 0.f};
        __syncthreads();

#pragma unroll 1
        for (int t = 0; t < T; ++t) {
            if ((t & (XCH - 1)) == 0) {       // stage next x chunk
                for (int i = tid; i < GW * XCH / 4; i += NT) {
                    int bb = i >> 6, t4 = (i & 63) * 4;
                    if (t + t4 < T) {
                        float4 v = *(const float4*)&x[(size_t)(b0 + bb) * T + t + t4];
                        xs[t4 + 0][bb] = v.x; xs[t4 + 1][bb] = v.y;
                        xs[t4 + 2][bb] = v.z; xs[t4 + 3][bb] = v.w;
                    }
                }
                __syncthreads();
            }
            if ((t & (CHUNK - 1)) == 0 && t + CHUNK > DRING)
                waitflag(consF, (u64)(t + CHUNK - DRING));   // ring-full throttle

            const int par = t & 1;
            f16x8 bh0 = *(const f16x8*)&bBuf[par][0][0][lane][0];
            f16x8 bh1 = *(const f16x8*)&bBuf[par][0][1][lane][0];
            f16x8 bl0 = *(const f16x8*)&bBuf[par][1][0][lane][0];
            f16x8 bl1 = *(const f16x8*)&bBuf[par][1][1][lane][0];
            float xv = xs[t & (XCH - 1)][n];
            float hq[2];
#pragma unroll
            for (int u = 0; u < 2; ++u) {
                f32x4 acc;
#pragma unroll
                for (int g = 0; g < 4; ++g) acc[g] = bias[u][g] + wxv[u][g] * xv;
                acc = MFMA(Ahi[u * 2 + 0], bh0, acc);
                acc = MFMA(Ahi[u * 2 + 1], bh1, acc);
                f32x4 a2 = z4;
                a2 = MFMA(Ahi[u * 2 + 0], bl0, a2);
                a2 = MFMA(Ahi[u * 2 + 1], bl1, a2);
                a2 = MFMA(Alo[u * 2 + 0], bh0, a2);
                a2 = MFMA(Alo[u * 2 + 1], bh1, a2);
                float gi = acc[0] + a2[0] * ISC, gf = acc[1] + a2[1] * ISC;
                float gg = acc[2] + a2[2] * ISC, go = acc[3] + a2[3] * ISC;
                float iv = fast_sig(gi), fv = fast_sig(gf);
                float gv = fast_tanh(gg), ov = fast_sig(go);
                c[u] = fv * c[u] + iv * gv;
                hq[u] = ov * fast_tanh(c[u]);
            }
            // publish h0(t): LDS (own next step) + global ring (consumer)
            f16 h0h = (f16)hq[0], h0l = (f16)((hq[0] - (float)h0h) * SCL);
            f16 h1h = (f16)hq[1], h1l = (f16)((hq[1] - (float)h1h) * SCL);
            u32 pH = packf16(h0h, h1h), pL = packf16(h0l, h1l);
            *(u32*)&bBuf[par ^ 1][0][kfL][row][2 * q] = pH;
            *(u32*)&bBuf[par ^ 1][1][kfL][row][2 * q] = pL;
            char* sb = ringG + (size_t)(t & (DRING - 1)) * 4096;
            __hip_atomic_store((u32*)(sb + ((0 + kfL) * 64 + row) * 16 + q * 4), pH,
                               __ATOMIC_RELAXED, __HIP_MEMORY_SCOPE_AGENT);
            __hip_atomic_store((u32*)(sb + ((2 + kfL) * 64 + row) * 16 + q * 4), pL,
                               __ATOMIC_RELAXED, __HIP_MEMORY_SCOPE_AGENT);
            __syncthreads();   // drains vmcnt for all waves before flag release
            if ((t & (CHUNK - 1)) == CHUNK - 1 && tid == 0)
                __hip_atomic_store(prodF, (u64)(t + 1),
                                   __ATOMIC_RELEASE, __HIP_MEMORY_SCOPE_AGENT);
        }
    } else {
        // ================= consumer: layer 1, K=128 =================
        f16x8 Ahi[8], Alo[8];
        f32x4 bias[2];
#pragma unroll
        for (int u = 0; u < 2; ++u) {
            const int tt = tt0 + u;
            const int rowA = gA * HD + tt * 4 + (n >> 2);
#pragma unroll
            for (int kf = 0; kf < 4; ++kf) {
                f16x8 hi, lo;
#pragma unroll
                for (int j = 0; j < 8; ++j) {
                    float v = (kf < 2)
                        ? Wih1[(size_t)rowA * HD + kinv(kf * 32 + q * 8 + j)]
                        : Whh1[(size_t)rowA * HD + kinv((kf - 2) * 32 + q * 8 + j)];
                    f16 h = (f16)v;
                    hi[j] = h; lo[j] = (f16)((v - (float)h) * SCL);
                }
                Ahi[u * 4 + kf] = hi; Alo[u * 4 + kf] = lo;
            }
            const int uc = tt * 4 + q;
#pragma unroll
            for (int g = 0; g < 4; ++g)
                bias[u][g] = bih1[g * HD + uc] + bhh1[g * HD + uc];
        }
        float c[2] = {0.f, 0.f};
        f16x8 pfh[2][2], pfl[2][2];   // prefetched h0 frags, 2 slots in flight

        auto loadslot = [&](int s, int buf) {
            char* sb = ringG + (size_t)(s & (DRING - 1)) * 4096 + (size_t)lane * 16;
#pragma unroll
            for (int kf = 0; kf < 2; ++kf) {
                union { u64 d[2]; f16x8 v; } Uh, Ul;
                u64* ph = (u64*)(sb + (0 + kf) * 1024);
                u64* pl = (u64*)(sb + (2 + kf) * 1024);
                Uh.d[0] = __hip_atomic_load(ph,     __ATOMIC_RELAXED, __HIP_MEMORY_SCOPE_AGENT);
                Uh.d[1] = __hip_atomic_load(ph + 1, __ATOMIC_RELAXED, __HIP_MEMORY_SCOPE_AGENT);
                Ul.d[0] = __hip_atomic_load(pl,     __ATOMIC_RELAXED, __HIP_MEMORY_SCOPE_AGENT);
                Ul.d[1] = __hip_atomic_load(pl + 1, __ATOMIC_RELAXED, __HIP_MEMORY_SCOPE_AGENT);
                pfh[buf][kf] = Uh.v; pfl[buf][kf] = Ul.v;
            }
        };
        __syncthreads();

#pragma unroll 1
        for (int cs = 0; cs < T; cs += CHUNK) {
            int tgt = cs + CHUNK + 2; if (tgt > T) tgt = T;
            waitflag(prodF, (u64)tgt);               // covers chunk + prefetch depth 2
            if (cs == 0) { loadslot(0, 0); loadslot(1, 1); }
#pragma unroll
            for (int cc = 0; cc < CHUNK; ++cc) {
                const int s = cs + cc;
                const int buf = s & 1, par = s & 1;
                f16x8 ch0 = *(const f16x8*)&bBuf[par][0][0][lane][0];
                f16x8 ch1 = *(const f16x8*)&bBuf[par][0][1][lane][0];
                f16x8 cl0 = *(const f16x8*)&bBuf[par][1][0][lane][0];
                f16x8 cl1 = *(const f16x8*)&bBuf[par][1][1][lane][0];
                float hq[2];
#pragma unroll
                for (int u = 0; u < 2; ++u) {
                    f32x4 acc = MFMA(Ahi[u * 4 + 0], pfh[buf][0], bias[u]);
                    acc = MFMA(Ahi[u * 4 + 1], pfh[buf][1], acc);
                    acc = MFMA(Ahi[u * 4 + 2], ch0, acc);
                    acc = MFMA(Ahi[u * 4 + 3], ch1, acc);
                    f32x4 a2 = MFMA(Ahi[u * 4 + 0], pfl[buf][0], z4);
                    a2 = MFMA(Ahi[u * 4 + 1], pfl[buf][1], a2);
                    a2 = MFMA(Ahi[u * 4 + 2], cl0, a2);
                    a2 = MFMA(Ahi[u * 4 + 3], cl1, a2);
                    a2 = MFMA(Alo[u * 4 + 0], pfh[buf][0], a2);
                    a2 = MFMA(Alo[u * 4 + 1], pfh[buf][1], a2);
                    a2 = MFMA(Alo[u * 4 + 2], ch0, a2);
                    a2 = MFMA(Alo[u * 4 + 3], ch1, a2);
                    float gi = acc[0] + a2[0] * ISC, gf = acc[1] + a2[1] * ISC;
                    float gg = acc[2] + a2[2] * ISC, go = acc[3] + a2[3] * ISC;
                    float iv = fast_sig(gi), fv = fast_sig(gf);
                    float gv = fast_tanh(gg), ov = fast_sig(go);
                    c[u] = fv * c[u] + iv * gv;
                    hq[u] = ov * fast_tanh(c[u]);
                }
                if (s + 2 < T) loadslot(s + 2, s & 1);   // prefetch (slot flag-covered)
                f16 h0h = (f16)hq[0], h0l = (f16)((hq[0] - (float)h0h) * SCL);
                f16 h1h = (f16)hq[1], h1l = (f16)((hq[1] - (float)h1h) * SCL);
                *(u32*)&bBuf[par ^ 1][0][kfL][row][2 * q] = packf16(h0h, h1h);
                *(u32*)&bBuf[par ^ 1][1][kfL][row][2 * q] = packf16(h0l, h1l);
                if (s == T - 1) {
                    hf[n][(tt0 + 0) * 4 + q] = hq[0];
                    hf[n][(tt0 + 1) * 4 + q] = hq[1];
                }
                __syncthreads();
            }
            if (tid == 0)
                __hip_atomic_store(consF, (u64)(cs + CHUNK),
                                   __ATOMIC_RELEASE, __HIP_MEMORY_SCOPE_AGENT);
        }

        // classifier: relu(h1 @ Wc1^T + bc1) @ Wc2^T + bc2
        if (tid < GW * 32) {
            int nn = tid >> 5, m = tid & 31;
            float acc = bc1[m];
            const float* wr = Wc1 + m * HD;
#pragma unroll
            for (int k = 0; k < HD; ++k) acc += wr[k] * hf[nn][k];
            hid[nn][m] = fmaxf(acc, 0.0f);
        }
        __syncthreads();
        if (tid < GW) {
            float acc = bc2[0];
#pragma unroll
            for (int k = 0; k < HD / 2; ++k) acc += Wc2[k] * hid[tid][k];
            out[b0 + tid] = acc;
        }
    }
}

extern "C" void kernel_launch(void* const* d_in, const int* in_sizes, int n_in,
                              void* d_out, int out_size, void* d_ws, size_t ws_size,
                              hipStream_t stream) {
    const float* x    = (const float*)d_in[0];
    const float* Wih0 = (const float*)d_in[1];
    const float* Whh0 = (const float*)d_in[2];
    const float* bih0 = (const float*)d_in[3];
    const float* bhh0 = (const float*)d_in[4];
    const float* Wih1 = (const float*)d_in[5];
    const float* Whh1 = (const float*)d_in[6];
    const float* bih1 = (const float*)d_in[7];
    const float* bhh1 = (const float*)d_in[8];
    const float* Wc1  = (const float*)d_in[9];
    const float* bc1  = (const float*)d_in[10];
    const float* Wc2  = (const float*)d_in[11];
    const float* bc2  = (const float*)d_in[12];

    const int B = out_size;            // output [B,1]
    const int T = in_sizes[0] / B;     // x is [B,T,1]
    const int groups = B / GW;

    hipLaunchKernelGGL(init_ws_k, dim3(32), dim3(256), 0, stream, (u64*)d_ws);
    hipLaunchKernelGGL(lstm2_pair, dim3(2 * groups), dim3(NT), 0, stream,
                       x, Wih0, Whh0, bih0, bhh0,
                       Wih1, Whh1, bih1, bhh1,
                       Wc1, bc1, Wc2, bc2,
                       (float*)d_out, (char*)d_ws, T);
}

// Round 5
// 2104.812 us; speedup vs baseline: 7.3505x; 7.3505x over previous
//
#include <hip/hip_runtime.h>

typedef _Float16 f16;
typedef _Float16 f16x8 __attribute__((ext_vector_type(8)));
typedef float    f32x4 __attribute__((ext_vector_type(4)));
typedef unsigned int       u32;
typedef unsigned long long u64;

#define HD    64
#define GW    16      // batches per group (full N-tile, zero padding)
#define NT    512     // 8 waves
#define CHUNK 4       // steps per flag update
#define XCH   256     // x staging chunk (timesteps)
#define SCL   2048.0f
#define ISC   (1.0f / 2048.0f)

__device__ __forceinline__ float fast_sig(float x) {
    return __builtin_amdgcn_rcpf(1.0f + __expf(-x));
}
__device__ __forceinline__ float fast_tanh(float x) {
    float e = __expf(2.0f * x);
    return (e - 1.0f) * __builtin_amdgcn_rcpf(e + 1.0f);
}
__device__ __forceinline__ f32x4 MFMA(f16x8 a, f16x8 b, f32x4 c) {
    return __builtin_amdgcn_mfma_f32_16x16x32_f16(a, b, c, 0, 0, 0);
}
// unit->k permutation (conflict-free packed publishes); kinv maps k -> unit
__device__ __forceinline__ int kinv(int k) {
    int kf = k >> 5, qk = (k >> 3) & 3, j = k & 7;
    int tile = (kf << 3) | (qk << 1) | (j & 1);
    return tile * 4 + (j >> 1);
}
__device__ __forceinline__ u32 packf16(f16 a, f16 b) {
    union { f16 h[2]; u32 u; } x; x.h[0] = a; x.h[1] = b; return x.u;
}
// tid-0-only poll: relaxed loads (no per-iteration cache inv), one acquire
// fence after the condition holds. Guard breaks (wrong answer, not a hang).
__device__ __forceinline__ void pollflag(u64* p, u64 need) {
    int guard = 0;
    while (__hip_atomic_load(p, __ATOMIC_RELAXED, __HIP_MEMORY_SCOPE_AGENT) < need) {
        __builtin_amdgcn_s_sleep(2);
        if (++guard > (1 << 21)) break;
    }
    __builtin_amdgcn_fence(__ATOMIC_ACQUIRE, "agent");
}

extern "C" __global__ void init_ws_k(u64* flags) {
    int i = blockIdx.x * 256 + threadIdx.x;
    if (i < 8192) flags[i] = 0;
}

extern "C" __global__ void __launch_bounds__(NT, 2)
lstm2_pair(const float* __restrict__ x,
           const float* __restrict__ Wih0, const float* __restrict__ Whh0,
           const float* __restrict__ bih0, const float* __restrict__ bhh0,
           const float* __restrict__ Wih1, const float* __restrict__ Whh1,
           const float* __restrict__ bih1, const float* __restrict__ bhh1,
           const float* __restrict__ Wc1,  const float* __restrict__ bc1,
           const float* __restrict__ Wc2,  const float* __restrict__ bc2,
           float* __restrict__ out, char* __restrict__ ws,
           int T, int groups, int slots)
{
    // per-role recurrent h frags, double buffered: [par][prec][kf][row][j]
    __shared__ __align__(16) f16 bBuf[2][2][2][64][8];   // 8 KB
    __shared__ float xs[XCH][GW];                        // 16 KB (producer only)
    __shared__ float hf[GW][HD];                         // final h1 (consumer)
    __shared__ float hid[GW][HD / 2];

    const int tid  = threadIdx.x;
    const int wave = tid >> 6;
    const int lane = tid & 63;
    const int q    = lane >> 4;
    const int n    = lane & 15;
    const int role  = blockIdx.x / groups;     // 0 = layer0 producer, 1 = layer1 consumer
    const int group = blockIdx.x % groups;     // pair (g, groups+g) -> same XCD (mod 8)
    const int b0    = group * GW;
    const int smask = slots - 1;

    u64* prodF = (u64*)(ws + (size_t)group * 128);
    u64* consF = (u64*)(ws + 32768 + (size_t)group * 128);
    char* ringG = ws + 65536 + (size_t)group * ((size_t)slots * 4096);

    { int* p = (int*)&bBuf[0][0][0][0][0];
      for (int i = tid; i < 2048; i += NT) p[i] = 0; }

    const int gA  = n & 3;              // gate of A-tile row (gate-interleaved)
    const int tt0 = 2 * wave;           // this wave's 2 tiles
    const int kfL = wave >> 2;          // publish kf
    const int qk  = wave & 3;
    const int row = qk * 16 + n;        // publish row
    const f32x4 z4 = {0.f, 0.f, 0.f, 0.f};

    if (role == 0) {
        // ================= producer: layer 0, K=64 =================
        f16x8 Ahi[4], Alo[4];
        f32x4 bias[2], wxv[2];
#pragma unroll
        for (int u = 0; u < 2; ++u) {
            const int tt = tt0 + u;
            const int rowA = gA * HD + tt * 4 + (n >> 2);
#pragma unroll
            for (int kf = 0; kf < 2; ++kf) {
                f16x8 hi, lo;
#pragma unroll
                for (int j = 0; j < 8; ++j) {
                    float v = Whh0[(size_t)rowA * HD + kinv(kf * 32 + q * 8 + j)];
                    f16 h = (f16)v;
                    hi[j] = h; lo[j] = (f16)((v - (float)h) * SCL);
                }
                Ahi[u * 2 + kf] = hi; Alo[u * 2 + kf] = lo;
            }
            const int uc = tt * 4 + q;
#pragma unroll
            for (int g = 0; g < 4; ++g) {
                bias[u][g] = bih0[g * HD + uc] + bhh0[g * HD + uc];
                wxv[u][g]  = Wih0[g * HD + uc];
            }
        }
        float c[2] = {0.f, 0.f};
        __syncthreads();

#pragma unroll 1
        for (int t = 0; t < T; ++t) {
            if ((t & (XCH - 1)) == 0) {       // stage next x chunk
                for (int i = tid; i < GW * XCH / 4; i += NT) {
                    int bb = i >> 6, t4 = (i & 63) * 4;
                    if (t + t4 < T) {
                        float4 v = *(const float4*)&x[(size_t)(b0 + bb) * T + t + t4];
                        xs[t4 + 0][bb] = v.x; xs[t4 + 1][bb] = v.y;
                        xs[t4 + 2][bb] = v.z; xs[t4 + 3][bb] = v.w;
                    }
                }
                __syncthreads();
            }
            // ring-full throttle: before writing slot t, consumer must have
            // finished step t+CHUNK-slots (covers whole chunk)
            if ((t & (CHUNK - 1)) == 0 && t + CHUNK > slots) {
                if (tid == 0) pollflag(consF, (u64)(t + CHUNK - slots));
                __syncthreads();
            }

            const int par = t & 1;
            f16x8 bh0 = *(const f16x8*)&bBuf[par][0][0][lane][0];
            f16x8 bh1 = *(const f16x8*)&bBuf[par][0][1][lane][0];
            f16x8 bl0 = *(const f16x8*)&bBuf[par][1][0][lane][0];
            f16x8 bl1 = *(const f16x8*)&bBuf[par][1][1][lane][0];
            float xv = xs[t & (XCH - 1)][n];
            float hq[2];
#pragma unroll
            for (int u = 0; u < 2; ++u) {
                f32x4 acc;
#pragma unroll
                for (int g = 0; g < 4; ++g) acc[g] = bias[u][g] + wxv[u][g] * xv;
                acc = MFMA(Ahi[u * 2 + 0], bh0, acc);
                acc = MFMA(Ahi[u * 2 + 1], bh1, acc);
                f32x4 a2 = z4;
                a2 = MFMA(Ahi[u * 2 + 0], bl0, a2);
                a2 = MFMA(Ahi[u * 2 + 1], bl1, a2);
                a2 = MFMA(Alo[u * 2 + 0], bh0, a2);
                a2 = MFMA(Alo[u * 2 + 1], bh1, a2);
                float gi = acc[0] + a2[0] * ISC, gf = acc[1] + a2[1] * ISC;
                float gg = acc[2] + a2[2] * ISC, go = acc[3] + a2[3] * ISC;
                float iv = fast_sig(gi), fv = fast_sig(gf);
                float gv = fast_tanh(gg), ov = fast_sig(go);
                c[u] = fv * c[u] + iv * gv;
                hq[u] = ov * fast_tanh(c[u]);
            }
            // publish h0(t): LDS (own next step) + ring (plain cached stores)
            f16 h0h = (f16)hq[0], h0l = (f16)((hq[0] - (float)h0h) * SCL);
            f16 h1h = (f16)hq[1], h1l = (f16)((hq[1] - (float)h1h) * SCL);
            u32 pH = packf16(h0h, h1h), pL = packf16(h0l, h1l);
            *(u32*)&bBuf[par ^ 1][0][kfL][row][2 * q] = pH;
            *(u32*)&bBuf[par ^ 1][1][kfL][row][2 * q] = pL;
            char* sb = ringG + (size_t)(t & smask) * 4096;
            *(u32*)(sb + ((0 + kfL) * 64 + row) * 16 + q * 4) = pH;
            *(u32*)(sb + ((2 + kfL) * 64 + row) * 16 + q * 4) = pL;
            __syncthreads();   // drains vmcnt for all waves before flag release
            if ((t & (CHUNK - 1)) == CHUNK - 1 && tid == 0)
                __hip_atomic_store(prodF, (u64)(t + 1),
                                   __ATOMIC_RELEASE, __HIP_MEMORY_SCOPE_AGENT);
        }
    } else {
        // ================= consumer: layer 1, K=128 =================
        f16x8 Ahi[8], Alo[8];
        f32x4 bias[2];
#pragma unroll
        for (int u = 0; u < 2; ++u) {
            const int tt = tt0 + u;
            const int rowA = gA * HD + tt * 4 + (n >> 2);
#pragma unroll
            for (int kf = 0; kf < 4; ++kf) {
                f16x8 hi, lo;
#pragma unroll
                for (int j = 0; j < 8; ++j) {
                    float v = (kf < 2)
                        ? Wih1[(size_t)rowA * HD + kinv(kf * 32 + q * 8 + j)]
                        : Whh1[(size_t)rowA * HD + kinv((kf - 2) * 32 + q * 8 + j)];
                    f16 h = (f16)v;
                    hi[j] = h; lo[j] = (f16)((v - (float)h) * SCL);
                }
                Ahi[u * 4 + kf] = hi; Alo[u * 4 + kf] = lo;
            }
            const int uc = tt * 4 + q;
#pragma unroll
            for (int g = 0; g < 4; ++g)
                bias[u][g] = bih1[g * HD + uc] + bhh1[g * HD + uc];
        }
        float c[2] = {0.f, 0.f};
        f16x8 pfh[2][2], pfl[2][2];   // prefetched h0 frags, 2 slots in flight

        auto loadslot = [&](int s, int buf) {   // plain cached dwordx4 loads
            const char* sb = ringG + (size_t)(s & smask) * 4096 + (size_t)lane * 16;
            pfh[buf][0] = *(const f16x8*)(sb + 0 * 1024);
            pfh[buf][1] = *(const f16x8*)(sb + 1 * 1024);
            pfl[buf][0] = *(const f16x8*)(sb + 2 * 1024);
            pfl[buf][1] = *(const f16x8*)(sb + 3 * 1024);
        };
        __syncthreads();

#pragma unroll 1
        for (int cs = 0; cs < T; cs += CHUNK) {
            int tgt = cs + CHUNK + 2; if (tgt > T) tgt = T;   // chunk + prefetch depth
            if (tid == 0) pollflag(prodF, (u64)tgt);
            __syncthreads();                                   // release all waves
            if (cs == 0) { loadslot(0, 0); loadslot(1, 1); }
#pragma unroll
            for (int cc = 0; cc < CHUNK; ++cc) {
                const int s = cs + cc;
                const int buf = s & 1, par = s & 1;
                f16x8 ch0 = *(const f16x8*)&bBuf[par][0][0][lane][0];
                f16x8 ch1 = *(const f16x8*)&bBuf[par][0][1][lane][0];
                f16x8 cl0 = *(const f16x8*)&bBuf[par][1][0][lane][0];
                f16x8 cl1 = *(const f16x8*)&bBuf[par][1][1][lane][0];
                float hq[2];
#pragma unroll
                for (int u = 0; u < 2; ++u) {
                    f32x4 acc = MFMA(Ahi[u * 4 + 0], pfh[buf][0], bias[u]);
                    acc = MFMA(Ahi[u * 4 + 1], pfh[buf][1], acc);
                    acc = MFMA(Ahi[u * 4 + 2], ch0, acc);
                    acc = MFMA(Ahi[u * 4 + 3], ch1, acc);
                    f32x4 a2 = MFMA(Ahi[u * 4 + 0], pfl[buf][0], z4);
                    a2 = MFMA(Ahi[u * 4 + 1], pfl[buf][1], a2);
                    a2 = MFMA(Ahi[u * 4 + 2], cl0, a2);
                    a2 = MFMA(Ahi[u * 4 + 3], cl1, a2);
                    a2 = MFMA(Alo[u * 4 + 0], pfh[buf][0], a2);
                    a2 = MFMA(Alo[u * 4 + 1], pfh[buf][1], a2);
                    a2 = MFMA(Alo[u * 4 + 2], ch0, a2);
                    a2 = MFMA(Alo[u * 4 + 3], ch1, a2);
                    float gi = acc[0] + a2[0] * ISC, gf = acc[1] + a2[1] * ISC;
                    float gg = acc[2] + a2[2] * ISC, go = acc[3] + a2[3] * ISC;
                    float iv = fast_sig(gi), fv = fast_sig(gf);
                    float gv = fast_tanh(gg), ov = fast_sig(go);
                    c[u] = fv * c[u] + iv * gv;
                    hq[u] = ov * fast_tanh(c[u]);
                }
                if (s + 2 < T) loadslot(s + 2, s & 1);   // covered by tgt wait
                f16 h0h = (f16)hq[0], h0l = (f16)((hq[0] - (float)h0h) * SCL);
                f16 h1h = (f16)hq[1], h1l = (f16)((hq[1] - (float)h1h) * SCL);
                *(u32*)&bBuf[par ^ 1][0][kfL][row][2 * q] = packf16(h0h, h1h);
                *(u32*)&bBuf[par ^ 1][1][kfL][row][2 * q] = packf16(h0l, h1l);
                if (s == T - 1) {
                    hf[n][(tt0 + 0) * 4 + q] = hq[0];
                    hf[n][(tt0 + 1) * 4 + q] = hq[1];
                }
                __syncthreads();
            }
            if (tid == 0)
                __hip_atomic_store(consF, (u64)(cs + CHUNK),
                                   __ATOMIC_RELEASE, __HIP_MEMORY_SCOPE_AGENT);
        }

        // classifier: relu(h1 @ Wc1^T + bc1) @ Wc2^T + bc2
        if (tid < GW * 32) {
            int nn = tid >> 5, m = tid & 31;
            float acc = bc1[m];
            const float* wr = Wc1 + m * HD;
#pragma unroll
            for (int k = 0; k < HD; ++k) acc += wr[k] * hf[nn][k];
            hid[nn][m] = fmaxf(acc, 0.0f);
        }
        __syncthreads();
        if (tid < GW) {
            float acc = bc2[0];
#pragma unroll
            for (int k = 0; k < HD / 2; ++k) acc += Wc2[k] * hid[tid][k];
            out[b0 + tid] = acc;
        }
    }
}

extern "C" void kernel_launch(void* const* d_in, const int* in_sizes, int n_in,
                              void* d_out, int out_size, void* d_ws, size_t ws_size,
                              hipStream_t stream) {
    const float* x    = (const float*)d_in[0];
    const float* Wih0 = (const float*)d_in[1];
    const float* Whh0 = (const float*)d_in[2];
    const float* bih0 = (const float*)d_in[3];
    const float* bhh0 = (const float*)d_in[4];
    const float* Wih1 = (const float*)d_in[5];
    const float* Whh1 = (const float*)d_in[6];
    const float* bih1 = (const float*)d_in[7];
    const float* bhh1 = (const float*)d_in[8];
    const float* Wc1  = (const float*)d_in[9];
    const float* bc1  = (const float*)d_in[10];
    const float* Wc2  = (const float*)d_in[11];
    const float* bc2  = (const float*)d_in[12];

    const int B = out_size;            // output [B,1]
    const int T = in_sizes[0] / B;     // x is [B,T,1]
    const int groups = B / GW;         // 128

    // ring depth from ws_size: 8 slots proven to fit (4.26 MB); go deeper if room
    int slots = 8;
    while (slots < 64 &&
           65536 + (size_t)groups * (size_t)(slots * 2) * 4096 <= ws_size)
        slots *= 2;

    hipLaunchKernelGGL(init_ws_k, dim3(32), dim3(256), 0, stream, (u64*)d_ws);
    hipLaunchKernelGGL(lstm2_pair, dim3(2 * groups), dim3(NT), 0, stream,
                       x, Wih0, Whh0, bih0, bhh0,
                       Wih1, Whh1, bih1, bhh1,
                       Wc1, bc1, Wc2, bc2,
                       (float*)d_out, (char*)d_ws, T, groups, slots);
}

// Round 6
// 1386.489 us; speedup vs baseline: 11.1587x; 1.5181x over previous
//
#include <hip/hip_runtime.h>

typedef _Float16 f16;
typedef _Float16 f16x8 __attribute__((ext_vector_type(8)));
typedef float    f32x4 __attribute__((ext_vector_type(4)));
typedef unsigned int       u32;
typedef unsigned long long u64;

#define HD    64
#define GW    16      // batches per group (full N-tile, zero padding)
#define NT    512     // 8 waves
#define CHUNK 8       // steps per flag update
#define XCH   256     // x staging chunk (timesteps)
#define SCL   2048.0f
#define ISC   (1.0f / 2048.0f)

__device__ __forceinline__ float fast_sig(float x) {
    return __builtin_amdgcn_rcpf(1.0f + __expf(-x));
}
__device__ __forceinline__ float fast_tanh(float x) {
    float e = __expf(2.0f * x);
    return (e - 1.0f) * __builtin_amdgcn_rcpf(e + 1.0f);
}
__device__ __forceinline__ f32x4 MFMA(f16x8 a, f16x8 b, f32x4 c) {
    return __builtin_amdgcn_mfma_f32_16x16x32_f16(a, b, c, 0, 0, 0);
}
// unit->k permutation (conflict-free packed publishes); kinv maps k -> unit
__device__ __forceinline__ int kinv(int k) {
    int kf = k >> 5, qk = (k >> 3) & 3, j = k & 7;
    int tile = (kf << 3) | (qk << 1) | (j & 1);
    return tile * 4 + (j >> 1);
}
__device__ __forceinline__ u32 packf16(f16 a, f16 b) {
    union { f16 h[2]; u32 u; } x; x.h[0] = a; x.h[1] = b; return x.u;
}
// relaxed poll, NO acquire fence: all ring data is read via sc1 (LLC) loads,
// so no cache invalidation is needed for freshness.
__device__ __forceinline__ void pollflag(u64* p, u64 need) {
    int guard = 0;
    while (__hip_atomic_load(p, __ATOMIC_RELAXED, __HIP_MEMORY_SCOPE_AGENT) < need) {
        __builtin_amdgcn_s_sleep(2);
        if (++guard > (1 << 20)) break;   // fail visibly, don't hang
    }
}

extern "C" __global__ void init_ws_k(u64* flags) {
    int i = blockIdx.x * 256 + threadIdx.x;
    if (i < 8192) flags[i] = 0;
}

extern "C" __global__ void __launch_bounds__(NT, 2)
lstm2_pair(const float* __restrict__ x,
           const float* __restrict__ Wih0, const float* __restrict__ Whh0,
           const float* __restrict__ bih0, const float* __restrict__ bhh0,
           const float* __restrict__ Wih1, const float* __restrict__ Whh1,
           const float* __restrict__ bih1, const float* __restrict__ bhh1,
           const float* __restrict__ Wc1,  const float* __restrict__ bc1,
           const float* __restrict__ Wc2,  const float* __restrict__ bc2,
           float* __restrict__ out, char* __restrict__ ws,
           int T, int groups, int slots)
{
    // per-role recurrent h frags, double buffered: [par][prec][kf][row][j]
    __shared__ __align__(16) f16 bBuf[2][2][2][64][8];   // 8 KB
    __shared__ float xs[XCH][GW];                        // 16 KB (producer only)
    __shared__ float hf[GW][HD];                         // final h1 (consumer)
    __shared__ float hid[GW][HD / 2];

    const int tid  = threadIdx.x;
    const int wave = tid >> 6;
    const int lane = tid & 63;
    const int q    = lane >> 4;
    const int n    = lane & 15;
    const int role  = blockIdx.x / groups;     // 0 = layer0 producer, 1 = layer1 consumer
    const int group = blockIdx.x % groups;     // pair (g, groups+g) -> same XCD (mod 8)
    const int b0    = group * GW;
    const int smask = slots - 1;

    u64* prodF = (u64*)(ws + (size_t)group * 128);
    u64* consF = (u64*)(ws + 32768 + (size_t)group * 128);
    char* ringG = ws + 65536 + (size_t)group * ((size_t)slots * 4096);

    { int* p = (int*)&bBuf[0][0][0][0][0];
      for (int i = tid; i < 2048; i += NT) p[i] = 0; }

    const int gA  = n & 3;              // gate of A-tile row (gate-interleaved)
    const int tt0 = 2 * wave;           // this wave's 2 tiles
    const int kfL = wave >> 2;          // publish kf
    const int qk  = wave & 3;
    const int row = qk * 16 + n;        // publish row
    const f32x4 z4 = {0.f, 0.f, 0.f, 0.f};

    if (role == 0) {
        // ================= producer: layer 0, K=64 =================
        f16x8 Ahi[4], Alo[4];
        f32x4 bias[2], wxv[2];
#pragma unroll
        for (int u = 0; u < 2; ++u) {
            const int tt = tt0 + u;
            const int rowA = gA * HD + tt * 4 + (n >> 2);
#pragma unroll
            for (int kf = 0; kf < 2; ++kf) {
                f16x8 hi, lo;
#pragma unroll
                for (int j = 0; j < 8; ++j) {
                    float v = Whh0[(size_t)rowA * HD + kinv(kf * 32 + q * 8 + j)];
                    f16 h = (f16)v;
                    hi[j] = h; lo[j] = (f16)((v - (float)h) * SCL);
                }
                Ahi[u * 2 + kf] = hi; Alo[u * 2 + kf] = lo;
            }
            const int uc = tt * 4 + q;
#pragma unroll
            for (int g = 0; g < 4; ++g) {
                bias[u][g] = bih0[g * HD + uc] + bhh0[g * HD + uc];
                wxv[u][g]  = Wih0[g * HD + uc];
            }
        }
        float c[2] = {0.f, 0.f};
        __syncthreads();

#pragma unroll 1
        for (int t = 0; t < T; ++t) {
            if ((t & (XCH - 1)) == 0) {       // stage next x chunk
                for (int i = tid; i < GW * XCH / 4; i += NT) {
                    int bb = i >> 6, t4 = (i & 63) * 4;
                    if (t + t4 < T) {
                        float4 v = *(const float4*)&x[(size_t)(b0 + bb) * T + t + t4];
                        xs[t4 + 0][bb] = v.x; xs[t4 + 1][bb] = v.y;
                        xs[t4 + 2][bb] = v.z; xs[t4 + 3][bb] = v.w;
                    }
                }
                __syncthreads();
            }
            // ring-full throttle (chunk granular)
            if ((t & (CHUNK - 1)) == 0 && t + CHUNK > slots) {
                if (tid == 0) pollflag(consF, (u64)(t + CHUNK - slots));
                __syncthreads();
            }

            const int par = t & 1;
            f16x8 bh0 = *(const f16x8*)&bBuf[par][0][0][lane][0];
            f16x8 bh1 = *(const f16x8*)&bBuf[par][0][1][lane][0];
            f16x8 bl0 = *(const f16x8*)&bBuf[par][1][0][lane][0];
            f16x8 bl1 = *(const f16x8*)&bBuf[par][1][1][lane][0];
            float xv = xs[t & (XCH - 1)][n];
            float hq[2];
#pragma unroll
            for (int u = 0; u < 2; ++u) {
                f32x4 acc;
#pragma unroll
                for (int g = 0; g < 4; ++g) acc[g] = bias[u][g] + wxv[u][g] * xv;
                acc = MFMA(Ahi[u * 2 + 0], bh0, acc);
                acc = MFMA(Ahi[u * 2 + 1], bh1, acc);
                f32x4 a2 = z4;
                a2 = MFMA(Ahi[u * 2 + 0], bl0, a2);
                a2 = MFMA(Ahi[u * 2 + 1], bl1, a2);
                a2 = MFMA(Alo[u * 2 + 0], bh0, a2);
                a2 = MFMA(Alo[u * 2 + 1], bh1, a2);
                float gi = acc[0] + a2[0] * ISC, gf = acc[1] + a2[1] * ISC;
                float gg = acc[2] + a2[2] * ISC, go = acc[3] + a2[3] * ISC;
                float iv = fast_sig(gi), fv = fast_sig(gf);
                float gv = fast_tanh(gg), ov = fast_sig(go);
                c[u] = fv * c[u] + iv * gv;
                hq[u] = ov * fast_tanh(c[u]);
            }
            // publish h0(t): LDS (own next step) + ring via sc1 stores (LLC)
            f16 h0h = (f16)hq[0], h0l = (f16)((hq[0] - (float)h0h) * SCL);
            f16 h1h = (f16)hq[1], h1l = (f16)((hq[1] - (float)h1h) * SCL);
            u32 pH = packf16(h0h, h1h), pL = packf16(h0l, h1l);
            *(u32*)&bBuf[par ^ 1][0][kfL][row][2 * q] = pH;
            *(u32*)&bBuf[par ^ 1][1][kfL][row][2 * q] = pL;
            char* sb = ringG + (size_t)(t & smask) * 4096;
            __hip_atomic_store((u32*)(sb + ((0 + kfL) * 64 + row) * 16 + q * 4), pH,
                               __ATOMIC_RELAXED, __HIP_MEMORY_SCOPE_AGENT);
            __hip_atomic_store((u32*)(sb + ((2 + kfL) * 64 + row) * 16 + q * 4), pL,
                               __ATOMIC_RELAXED, __HIP_MEMORY_SCOPE_AGENT);
            __syncthreads();   // every wave drains its own vmcnt before barrier
            if ((t & (CHUNK - 1)) == CHUNK - 1 && tid == 0)
                __hip_atomic_store(prodF, (u64)(t + 1),
                                   __ATOMIC_RELEASE, __HIP_MEMORY_SCOPE_AGENT);
        }
    } else {
        // ================= consumer: layer 1, K=128 =================
        f16x8 Ahi[8], Alo[8];
        f32x4 bias[2];
#pragma unroll
        for (int u = 0; u < 2; ++u) {
            const int tt = tt0 + u;
            const int rowA = gA * HD + tt * 4 + (n >> 2);
#pragma unroll
            for (int kf = 0; kf < 4; ++kf) {
                f16x8 hi, lo;
#pragma unroll
                for (int j = 0; j < 8; ++j) {
                    float v = (kf < 2)
                        ? Wih1[(size_t)rowA * HD + kinv(kf * 32 + q * 8 + j)]
                        : Whh1[(size_t)rowA * HD + kinv((kf - 2) * 32 + q * 8 + j)];
                    f16 h = (f16)v;
                    hi[j] = h; lo[j] = (f16)((v - (float)h) * SCL);
                }
                Ahi[u * 4 + kf] = hi; Alo[u * 4 + kf] = lo;
            }
            const int uc = tt * 4 + q;
#pragma unroll
            for (int g = 0; g < 4; ++g)
                bias[u][g] = bih1[g * HD + uc] + bhh1[g * HD + uc];
        }
        float c[2] = {0.f, 0.f};
        f16x8 pfh[2][2], pfl[2][2];   // prefetched h0 frags, 2 slots in flight

        auto loadslot = [&](int s, int buf) {   // sc1 (LLC) loads, L1/L2 bypass
            char* sb = ringG + (size_t)(s & smask) * 4096 + (size_t)lane * 16;
#pragma unroll
            for (int kf = 0; kf < 2; ++kf) {
                union { u64 d[2]; f16x8 v; } Uh, Ul;
                u64* ph = (u64*)(sb + (0 + kf) * 1024);
                u64* pl = (u64*)(sb + (2 + kf) * 1024);
                Uh.d[0] = __hip_atomic_load(ph,     __ATOMIC_RELAXED, __HIP_MEMORY_SCOPE_AGENT);
                Uh.d[1] = __hip_atomic_load(ph + 1, __ATOMIC_RELAXED, __HIP_MEMORY_SCOPE_AGENT);
                Ul.d[0] = __hip_atomic_load(pl,     __ATOMIC_RELAXED, __HIP_MEMORY_SCOPE_AGENT);
                Ul.d[1] = __hip_atomic_load(pl + 1, __ATOMIC_RELAXED, __HIP_MEMORY_SCOPE_AGENT);
                pfh[buf][kf] = Uh.v; pfl[buf][kf] = Ul.v;
            }
        };
        __syncthreads();

#pragma unroll 1
        for (int cs = 0; cs < T; cs += CHUNK) {
            int tgt = cs + CHUNK + 2; if (tgt > T) tgt = T;   // chunk + prefetch depth
            if (tid == 0) pollflag(prodF, (u64)tgt);
            __syncthreads();                                   // release all waves
            if (cs == 0) { loadslot(0, 0); loadslot(1, 1); }
#pragma unroll
            for (int cc = 0; cc < CHUNK; ++cc) {
                const int s = cs + cc;
                const int buf = s & 1, par = s & 1;
                f16x8 ch0 = *(const f16x8*)&bBuf[par][0][0][lane][0];
                f16x8 ch1 = *(const f16x8*)&bBuf[par][0][1][lane][0];
                f16x8 cl0 = *(const f16x8*)&bBuf[par][1][0][lane][0];
                f16x8 cl1 = *(const f16x8*)&bBuf[par][1][1][lane][0];
                float hq[2];
#pragma unroll
                for (int u = 0; u < 2; ++u) {
                    f32x4 acc = MFMA(Ahi[u * 4 + 0], pfh[buf][0], bias[u]);
                    acc = MFMA(Ahi[u * 4 + 1], pfh[buf][1], acc);
                    acc = MFMA(Ahi[u * 4 + 2], ch0, acc);
                    acc = MFMA(Ahi[u * 4 + 3], ch1, acc);
                    f32x4 a2 = MFMA(Ahi[u * 4 + 0], pfl[buf][0], z4);
                    a2 = MFMA(Ahi[u * 4 + 1], pfl[buf][1], a2);
                    a2 = MFMA(Ahi[u * 4 + 2], cl0, a2);
                    a2 = MFMA(Ahi[u * 4 + 3], cl1, a2);
                    a2 = MFMA(Alo[u * 4 + 0], pfh[buf][0], a2);
                    a2 = MFMA(Alo[u * 4 + 1], pfh[buf][1], a2);
                    a2 = MFMA(Alo[u * 4 + 2], ch0, a2);
                    a2 = MFMA(Alo[u * 4 + 3], ch1, a2);
                    float gi = acc[0] + a2[0] * ISC, gf = acc[1] + a2[1] * ISC;
                    float gg = acc[2] + a2[2] * ISC, go = acc[3] + a2[3] * ISC;
                    float iv = fast_sig(gi), fv = fast_sig(gf);
                    float gv = fast_tanh(gg), ov = fast_sig(go);
                    c[u] = fv * c[u] + iv * gv;
                    hq[u] = ov * fast_tanh(c[u]);
                }
                if (s + 2 < T) loadslot(s + 2, s & 1);   // covered by tgt wait
                f16 h0h = (f16)hq[0], h0l = (f16)((hq[0] - (float)h0h) * SCL);
                f16 h1h = (f16)hq[1], h1l = (f16)((hq[1] - (float)h1h) * SCL);
                *(u32*)&bBuf[par ^ 1][0][kfL][row][2 * q] = packf16(h0h, h1h);
                *(u32*)&bBuf[par ^ 1][1][kfL][row][2 * q] = packf16(h0l, h1l);
                if (s == T - 1) {
                    hf[n][(tt0 + 0) * 4 + q] = hq[0];
                    hf[n][(tt0 + 1) * 4 + q] = hq[1];
                }
                __syncthreads();
            }
            if (tid == 0)
                __hip_atomic_store(consF, (u64)(cs + CHUNK),
                                   __ATOMIC_RELEASE, __HIP_MEMORY_SCOPE_AGENT);
        }

        // classifier: relu(h1 @ Wc1^T + bc1) @ Wc2^T + bc2
        if (tid < GW * 32) {
            int nn = tid >> 5, m = tid & 31;
            float acc = bc1[m];
            const float* wr = Wc1 + m * HD;
#pragma unroll
            for (int k = 0; k < HD; ++k) acc += wr[k] * hf[nn][k];
            hid[nn][m] = fmaxf(acc, 0.0f);
        }
        __syncthreads();
        if (tid < GW) {
            float acc = bc2[0];
#pragma unroll
            for (int k = 0; k < HD / 2; ++k) acc += Wc2[k] * hid[tid][k];
            out[b0 + tid] = acc;
        }
    }
}

extern "C" void kernel_launch(void* const* d_in, const int* in_sizes, int n_in,
                              void* d_out, int out_size, void* d_ws, size_t ws_size,
                              hipStream_t stream) {
    const float* x    = (const float*)d_in[0];
    const float* Wih0 = (const float*)d_in[1];
    const float* Whh0 = (const float*)d_in[2];
    const float* bih0 = (const float*)d_in[3];
    const float* bhh0 = (const float*)d_in[4];
    const float* Wih1 = (const float*)d_in[5];
    const float* Whh1 = (const float*)d_in[6];
    const float* bih1 = (const float*)d_in[7];
    const float* bhh1 = (const float*)d_in[8];
    const float* Wc1  = (const float*)d_in[9];
    const float* bc1  = (const float*)d_in[10];
    const float* Wc2  = (const float*)d_in[11];
    const float* bc2  = (const float*)d_in[12];

    const int B = out_size;            // output [B,1]
    const int T = in_sizes[0] / B;     // x is [B,T,1]
    const int groups = B / GW;         // 128

    // ring depth from ws_size: 8 slots (4.26 MB) minimum; deeper if room
    int slots = 8;
    while (slots < 64 &&
           65536 + (size_t)groups * (size_t)(slots * 2) * 4096 <= ws_size)
        slots *= 2;

    hipLaunchKernelGGL(init_ws_k, dim3(32), dim3(256), 0, stream, (u64*)d_ws);
    hipLaunchKernelGGL(lstm2_pair, dim3(2 * groups), dim3(NT), 0, stream,
                       x, Wih0, Whh0, bih0, bhh0,
                       Wih1, Whh1, bih1, bhh1,
                       Wc1, bc1, Wc2, bc2,
                       (float*)d_out, (char*)d_ws, T, groups, slots);
}

// Round 7
// 986.953 us; speedup vs baseline: 15.6759x; 1.4048x over previous
//
#include <hip/hip_runtime.h>

typedef _Float16 f16;
typedef _Float16 f16x8 __attribute__((ext_vector_type(8)));
typedef float    f32x4 __attribute__((ext_vector_type(4)));
typedef unsigned int       u32;
typedef unsigned long long u64;

#define HD    64
#define GW    16      // batches per group (full N-tile, zero padding)
#define NT    512     // 8 waves
#define CHUNK 8       // steps per flag update
#define XCH   256     // x staging chunk (timesteps)
#define SCL   2048.0f
#define ISC   (1.0f / 2048.0f)

// Barrier that waits ONLY on LDS (lgkmcnt) — in-flight global sc1 traffic
// (vmcnt) stays outstanding across it. This is the whole round-7 fix:
// __syncthreads() would drain vmcnt(0) and put the ~700-cyc LLC ack on the
// per-step critical path.
#define BAR_LGKM() asm volatile("s_waitcnt lgkmcnt(0)\ns_barrier" ::: "memory")
// Full drain barrier for flag releases (all waves' sc1 stores visible).
#define BAR_FULL() asm volatile("s_waitcnt vmcnt(0) lgkmcnt(0)\ns_barrier" ::: "memory")

__device__ __forceinline__ float fast_sig(float x) {
    return __builtin_amdgcn_rcpf(1.0f + __expf(-x));
}
__device__ __forceinline__ float fast_tanh(float x) {
    float e = __expf(2.0f * x);
    return (e - 1.0f) * __builtin_amdgcn_rcpf(e + 1.0f);
}
__device__ __forceinline__ f32x4 MFMA(f16x8 a, f16x8 b, f32x4 c) {
    return __builtin_amdgcn_mfma_f32_16x16x32_f16(a, b, c, 0, 0, 0);
}
// unit->k permutation (conflict-free packed publishes); kinv maps k -> unit
__device__ __forceinline__ int kinv(int k) {
    int kf = k >> 5, qk = (k >> 3) & 3, j = k & 7;
    int tile = (kf << 3) | (qk << 1) | (j & 1);
    return tile * 4 + (j >> 1);
}
__device__ __forceinline__ u32 packf16(f16 a, f16 b) {
    union { f16 h[2]; u32 u; } x; x.h[0] = a; x.h[1] = b; return x.u;
}
// relaxed poll, NO acquire fence: all ring data is read via sc1 (LLC) loads,
// so no cache invalidation is needed for freshness.
__device__ __forceinline__ void pollflag(u64* p, u64 need) {
    int guard = 0;
    while (__hip_atomic_load(p, __ATOMIC_RELAXED, __HIP_MEMORY_SCOPE_AGENT) < need) {
        __builtin_amdgcn_s_sleep(2);
        if (++guard > (1 << 20)) break;   // fail visibly, don't hang
    }
}

extern "C" __global__ void init_ws_k(u64* flags) {
    int i = blockIdx.x * 256 + threadIdx.x;
    if (i < 8192) flags[i] = 0;
}

extern "C" __global__ void __launch_bounds__(NT, 2)
lstm2_pair(const float* __restrict__ x,
           const float* __restrict__ Wih0, const float* __restrict__ Whh0,
           const float* __restrict__ bih0, const float* __restrict__ bhh0,
           const float* __restrict__ Wih1, const float* __restrict__ Whh1,
           const float* __restrict__ bih1, const float* __restrict__ bhh1,
           const float* __restrict__ Wc1,  const float* __restrict__ bc1,
           const float* __restrict__ Wc2,  const float* __restrict__ bc2,
           float* __restrict__ out, char* __restrict__ ws,
           int T, int groups, int slots)
{
    // per-role recurrent h frags, double buffered: [par][prec][kf][row][j]
    __shared__ __align__(16) f16 bBuf[2][2][2][64][8];   // 8 KB
    __shared__ float xs[XCH][GW];                        // 16 KB (producer only)
    __shared__ float hf[GW][HD];                         // final h1 (consumer)
    __shared__ float hid[GW][HD / 2];

    const int tid  = threadIdx.x;
    const int wave = tid >> 6;
    const int lane = tid & 63;
    const int q    = lane >> 4;
    const int n    = lane & 15;
    const int role  = blockIdx.x / groups;     // 0 = layer0 producer, 1 = layer1 consumer
    const int group = blockIdx.x % groups;     // pair (g, groups+g) -> same XCD (mod 8)
    const int b0    = group * GW;
    const int smask = slots - 1;

    u64* prodF = (u64*)(ws + (size_t)group * 128);
    u64* consF = (u64*)(ws + 32768 + (size_t)group * 128);
    char* ringG = ws + 65536 + (size_t)group * ((size_t)slots * 4096);

    { int* p = (int*)&bBuf[0][0][0][0][0];
      for (int i = tid; i < 2048; i += NT) p[i] = 0; }

    const int gA  = n & 3;              // gate of A-tile row (gate-interleaved)
    const int tt0 = 2 * wave;           // this wave's 2 tiles
    const int kfL = wave >> 2;          // publish kf
    const int qk  = wave & 3;
    const int row = qk * 16 + n;        // publish row
    const f32x4 z4 = {0.f, 0.f, 0.f, 0.f};

    if (role == 0) {
        // ================= producer: layer 0, K=64 =================
        f16x8 Ahi[4], Alo[4];
        f32x4 bias[2], wxv[2];
#pragma unroll
        for (int u = 0; u < 2; ++u) {
            const int tt = tt0 + u;
            const int rowA = gA * HD + tt * 4 + (n >> 2);
#pragma unroll
            for (int kf = 0; kf < 2; ++kf) {
                f16x8 hi, lo;
#pragma unroll
                for (int j = 0; j < 8; ++j) {
                    float v = Whh0[(size_t)rowA * HD + kinv(kf * 32 + q * 8 + j)];
                    f16 h = (f16)v;
                    hi[j] = h; lo[j] = (f16)((v - (float)h) * SCL);
                }
                Ahi[u * 2 + kf] = hi; Alo[u * 2 + kf] = lo;
            }
            const int uc = tt * 4 + q;
#pragma unroll
            for (int g = 0; g < 4; ++g) {
                bias[u][g] = bih0[g * HD + uc] + bhh0[g * HD + uc];
                wxv[u][g]  = Wih0[g * HD + uc];
            }
        }
        float c[2] = {0.f, 0.f};
        __syncthreads();

#pragma unroll 1
        for (int t = 0; t < T; ++t) {
            if ((t & (XCH - 1)) == 0) {       // stage next x chunk
                for (int i = tid; i < GW * XCH / 4; i += NT) {
                    int bb = i >> 6, t4 = (i & 63) * 4;
                    if (t + t4 < T) {
                        float4 v = *(const float4*)&x[(size_t)(b0 + bb) * T + t + t4];
                        xs[t4 + 0][bb] = v.x; xs[t4 + 1][bb] = v.y;
                        xs[t4 + 2][bb] = v.z; xs[t4 + 3][bb] = v.w;
                    }
                }
                BAR_LGKM();
            }
            // ring-full throttle (chunk granular; pure execution sync)
            if ((t & (CHUNK - 1)) == 0 && t + CHUNK > slots) {
                if (tid == 0) pollflag(consF, (u64)(t + CHUNK - slots));
                BAR_LGKM();
            }

            const int par = t & 1;
            f16x8 bh0 = *(const f16x8*)&bBuf[par][0][0][lane][0];
            f16x8 bh1 = *(const f16x8*)&bBuf[par][0][1][lane][0];
            f16x8 bl0 = *(const f16x8*)&bBuf[par][1][0][lane][0];
            f16x8 bl1 = *(const f16x8*)&bBuf[par][1][1][lane][0];
            float xv = xs[t & (XCH - 1)][n];
            float hq[2];
#pragma unroll
            for (int u = 0; u < 2; ++u) {
                f32x4 acc;
#pragma unroll
                for (int g = 0; g < 4; ++g) acc[g] = bias[u][g] + wxv[u][g] * xv;
                acc = MFMA(Ahi[u * 2 + 0], bh0, acc);
                acc = MFMA(Ahi[u * 2 + 1], bh1, acc);
                f32x4 a2 = z4;
                a2 = MFMA(Ahi[u * 2 + 0], bl0, a2);
                a2 = MFMA(Ahi[u * 2 + 1], bl1, a2);
                a2 = MFMA(Alo[u * 2 + 0], bh0, a2);
                a2 = MFMA(Alo[u * 2 + 1], bh1, a2);
                float gi = acc[0] + a2[0] * ISC, gf = acc[1] + a2[1] * ISC;
                float gg = acc[2] + a2[2] * ISC, go = acc[3] + a2[3] * ISC;
                float iv = fast_sig(gi), fv = fast_sig(gf);
                float gv = fast_tanh(gg), ov = fast_sig(go);
                c[u] = fv * c[u] + iv * gv;
                hq[u] = ov * fast_tanh(c[u]);
            }
            // publish h0(t): LDS (own next step) + ring via sc1 stores (LLC).
            // sc1 stores stay in flight across the lgkm-only barrier.
            f16 h0h = (f16)hq[0], h0l = (f16)((hq[0] - (float)h0h) * SCL);
            f16 h1h = (f16)hq[1], h1l = (f16)((hq[1] - (float)h1h) * SCL);
            u32 pH = packf16(h0h, h1h), pL = packf16(h0l, h1l);
            *(u32*)&bBuf[par ^ 1][0][kfL][row][2 * q] = pH;
            *(u32*)&bBuf[par ^ 1][1][kfL][row][2 * q] = pL;
            char* sb = ringG + (size_t)(t & smask) * 4096;
            __hip_atomic_store((u32*)(sb + ((0 + kfL) * 64 + row) * 16 + q * 4), pH,
                               __ATOMIC_RELAXED, __HIP_MEMORY_SCOPE_AGENT);
            __hip_atomic_store((u32*)(sb + ((2 + kfL) * 64 + row) * 16 + q * 4), pL,
                               __ATOMIC_RELAXED, __HIP_MEMORY_SCOPE_AGENT);
            if ((t & (CHUNK - 1)) == CHUNK - 1) {
                BAR_FULL();   // all waves' ring stores acked at LLC
                if (tid == 0)
                    __hip_atomic_store(prodF, (u64)(t + 1),
                                       __ATOMIC_RELAXED, __HIP_MEMORY_SCOPE_AGENT);
            } else {
                BAR_LGKM();   // LDS visibility only; vmcnt stays outstanding
            }
        }
    } else {
        // ================= consumer: layer 1, K=128 =================
        f16x8 Ahi[8], Alo[8];
        f32x4 bias[2];
#pragma unroll
        for (int u = 0; u < 2; ++u) {
            const int tt = tt0 + u;
            const int rowA = gA * HD + tt * 4 + (n >> 2);
#pragma unroll
            for (int kf = 0; kf < 4; ++kf) {
                f16x8 hi, lo;
#pragma unroll
                for (int j = 0; j < 8; ++j) {
                    float v = (kf < 2)
                        ? Wih1[(size_t)rowA * HD + kinv(kf * 32 + q * 8 + j)]
                        : Whh1[(size_t)rowA * HD + kinv((kf - 2) * 32 + q * 8 + j)];
                    f16 h = (f16)v;
                    hi[j] = h; lo[j] = (f16)((v - (float)h) * SCL);
                }
                Ahi[u * 4 + kf] = hi; Alo[u * 4 + kf] = lo;
            }
            const int uc = tt * 4 + q;
#pragma unroll
            for (int g = 0; g < 4; ++g)
                bias[u][g] = bih1[g * HD + uc] + bhh1[g * HD + uc];
        }
        float c[2] = {0.f, 0.f};
        f16x8 pfh[2][2], pfl[2][2];   // prefetched h0 frags, 2 slots in flight

        auto loadslot = [&](int s, int buf) {   // sc1 (LLC) loads, L1/L2 bypass
            char* sb = ringG + (size_t)(s & smask) * 4096 + (size_t)lane * 16;
#pragma unroll
            for (int kf = 0; kf < 2; ++kf) {
                union { u64 d[2]; f16x8 v; } Uh, Ul;
                u64* ph = (u64*)(sb + (0 + kf) * 1024);
                u64* pl = (u64*)(sb + (2 + kf) * 1024);
                Uh.d[0] = __hip_atomic_load(ph,     __ATOMIC_RELAXED, __HIP_MEMORY_SCOPE_AGENT);
                Uh.d[1] = __hip_atomic_load(ph + 1, __ATOMIC_RELAXED, __HIP_MEMORY_SCOPE_AGENT);
                Ul.d[0] = __hip_atomic_load(pl,     __ATOMIC_RELAXED, __HIP_MEMORY_SCOPE_AGENT);
                Ul.d[1] = __hip_atomic_load(pl + 1, __ATOMIC_RELAXED, __HIP_MEMORY_SCOPE_AGENT);
                pfh[buf][kf] = Uh.v; pfl[buf][kf] = Ul.v;
            }
        };
        __syncthreads();

#pragma unroll 1
        for (int cs = 0; cs < T; cs += CHUNK) {
            int tgt = cs + CHUNK + 2; if (tgt > T) tgt = T;   // chunk + prefetch depth
            if (tid == 0) pollflag(prodF, (u64)tgt);
            BAR_LGKM();                                        // release all waves
            if (cs == 0) { loadslot(0, 0); loadslot(1, 1); }
#pragma unroll
            for (int cc = 0; cc < CHUNK; ++cc) {
                const int s = cs + cc;
                const int buf = s & 1, par = s & 1;
                f16x8 ch0 = *(const f16x8*)&bBuf[par][0][0][lane][0];
                f16x8 ch1 = *(const f16x8*)&bBuf[par][0][1][lane][0];
                f16x8 cl0 = *(const f16x8*)&bBuf[par][1][0][lane][0];
                f16x8 cl1 = *(const f16x8*)&bBuf[par][1][1][lane][0];
                float hq[2];
#pragma unroll
                for (int u = 0; u < 2; ++u) {
                    f32x4 acc = MFMA(Ahi[u * 4 + 0], pfh[buf][0], bias[u]);
                    acc = MFMA(Ahi[u * 4 + 1], pfh[buf][1], acc);
                    acc = MFMA(Ahi[u * 4 + 2], ch0, acc);
                    acc = MFMA(Ahi[u * 4 + 3], ch1, acc);
                    f32x4 a2 = MFMA(Ahi[u * 4 + 0], pfl[buf][0], z4);
                    a2 = MFMA(Ahi[u * 4 + 1], pfl[buf][1], a2);
                    a2 = MFMA(Ahi[u * 4 + 2], cl0, a2);
                    a2 = MFMA(Ahi[u * 4 + 3], cl1, a2);
                    a2 = MFMA(Alo[u * 4 + 0], pfh[buf][0], a2);
                    a2 = MFMA(Alo[u * 4 + 1], pfh[buf][1], a2);
                    a2 = MFMA(Alo[u * 4 + 2], ch0, a2);
                    a2 = MFMA(Alo[u * 4 + 3], ch1, a2);
                    float gi = acc[0] + a2[0] * ISC, gf = acc[1] + a2[1] * ISC;
                    float gg = acc[2] + a2[2] * ISC, go = acc[3] + a2[3] * ISC;
                    float iv = fast_sig(gi), fv = fast_sig(gf);
                    float gv = fast_tanh(gg), ov = fast_sig(go);
                    c[u] = fv * c[u] + iv * gv;
                    hq[u] = ov * fast_tanh(c[u]);
                }
                // prefetch slot s+2 into the buf being retired this step;
                // stays in flight across the lgkm-only barrier (the fix).
                if (s + 2 < T) loadslot(s + 2, s & 1);
                f16 h0h = (f16)hq[0], h0l = (f16)((hq[0] - (float)h0h) * SCL);
                f16 h1h = (f16)hq[1], h1l = (f16)((hq[1] - (float)h1h) * SCL);
                *(u32*)&bBuf[par ^ 1][0][kfL][row][2 * q] = packf16(h0h, h1h);
                *(u32*)&bBuf[par ^ 1][1][kfL][row][2 * q] = packf16(h0l, h1l);
                if (s == T - 1) {
                    hf[n][(tt0 + 0) * 4 + q] = hq[0];
                    hf[n][(tt0 + 1) * 4 + q] = hq[1];
                }
                BAR_LGKM();
            }
            // chunk's ring reads were consumed (data-dep waits) before the
            // final per-step barrier; safe to signal with a relaxed store.
            if (tid == 0)
                __hip_atomic_store(consF, (u64)(cs + CHUNK),
                                   __ATOMIC_RELAXED, __HIP_MEMORY_SCOPE_AGENT);
        }

        // classifier: relu(h1 @ Wc1^T + bc1) @ Wc2^T + bc2
        __syncthreads();
        if (tid < GW * 32) {
            int nn = tid >> 5, m = tid & 31;
            float acc = bc1[m];
            const float* wr = Wc1 + m * HD;
#pragma unroll
            for (int k = 0; k < HD; ++k) acc += wr[k] * hf[nn][k];
            hid[nn][m] = fmaxf(acc, 0.0f);
        }
        __syncthreads();
        if (tid < GW) {
            float acc = bc2[0];
#pragma unroll
            for (int k = 0; k < HD / 2; ++k) acc += Wc2[k] * hid[tid][k];
            out[b0 + tid] = acc;
        }
    }
}

extern "C" void kernel_launch(void* const* d_in, const int* in_sizes, int n_in,
                              void* d_out, int out_size, void* d_ws, size_t ws_size,
                              hipStream_t stream) {
    const float* x    = (const float*)d_in[0];
    const float* Wih0 = (const float*)d_in[1];
    const float* Whh0 = (const float*)d_in[2];
    const float* bih0 = (const float*)d_in[3];
    const float* bhh0 = (const float*)d_in[4];
    const float* Wih1 = (const float*)d_in[5];
    const float* Whh1 = (const float*)d_in[6];
    const float* bih1 = (const float*)d_in[7];
    const float* bhh1 = (const float*)d_in[8];
    const float* Wc1  = (const float*)d_in[9];
    const float* bc1  = (const float*)d_in[10];
    const float* Wc2  = (const float*)d_in[11];
    const float* bc2  = (const float*)d_in[12];

    const int B = out_size;            // output [B,1]
    const int T = in_sizes[0] / B;     // x is [B,T,1]
    const int groups = B / GW;         // 128

    // ring depth from ws_size: 8 slots (4.26 MB) minimum; deeper if room
    int slots = 8;
    while (slots < 64 &&
           65536 + (size_t)groups * (size_t)(slots * 2) * 4096 <= ws_size)
        slots *= 2;

    hipLaunchKernelGGL(init_ws_k, dim3(32), dim3(256), 0, stream, (u64*)d_ws);
    hipLaunchKernelGGL(lstm2_pair, dim3(2 * groups), dim3(NT), 0, stream,
                       x, Wih0, Whh0, bih0, bhh0,
                       Wih1, Whh1, bih1, bhh1,
                       Wc1, bc1, Wc2, bc2,
                       (float*)d_out, (char*)d_ws, T, groups, slots);
}